// Round 11
// baseline (2936.624 us; speedup 1.0000x reference)
//
#include <hip/hip_runtime.h>
#include <hip/hip_bf16.h>

// ---------------------------------------------------------------------------
// FaceXHuBERT decoder: 2-layer GRU (H=256) over T=512 + fc to V=70110 with
// teacher-forcing feedback through red_w [A=768, V].
//
// Pipeline (see round 7/9 headers for the algebra):
//   bigk_merged / gemv3 / transpose_merged / gemm128x3 prologue (round 10)
//   k3_fused: 32 producer WGs (GRU recurrence) + 224 consumer WGs (fc GEMM)
//
// Round 11: A-AHEAD SOFTWARE PIPELINE in the producers. Each iteration t
// computes A(t+1) (layer-0 step) and B(t) (layer-1 step) from the SAME h0_t,
// publishes h0_{t+1} and h1_t back-to-back, then DUAL-POLLS both tagged
// buffers (two loads in flight -> one shared IC round trip). tf[t]=1 steps
// thus pay ~1 exchange window instead of 2; tf[t]=0 steps keep the
// h1->A(t+1) ordering (2 RTTs, h1 detect overlapped under the wh0s half).
// combineA on tid<16, combineB on tid 16..31 (4 disjoint dotsS slots).
// Tag/parity protocol unchanged (WAR chain verified for both branches).
// ---------------------------------------------------------------------------

#define TT 512
#define VD 70110
#define NR 1024  // B*T

using bf16x8 = __attribute__((ext_vector_type(8))) short;
using f32x4  = __attribute__((ext_vector_type(4))) float;

static __device__ __forceinline__ unsigned short f2bf(float f) {
  unsigned u = __float_as_uint(f);
  u += 0x7FFFu + ((u >> 16) & 1u);   // RNE
  return (unsigned short)(u >> 16);
}

// ---------------- merged big split-K GEMM over V (bf16 MFMA, atomicAdd) -----
__global__ __launch_bounds__(512, 1)
void bigk_merged(const float* __restrict__ A, const float* __restrict__ vert,
                 const float* __restrict__ fcw,
                 float* __restrict__ OUTG, float* __restrict__ OUTM, int CHK)
{
  __shared__ unsigned short Al[256][40];
  __shared__ unsigned short Bl[256][40];
  const int tid = threadIdx.x;
  const bool bform = (blockIdx.x == 4);
  float* C      = bform ? OUTM : OUTG;
  const int ldc = bform ? 256 : 1024;
  const int N   = bform ? 256 : 1024;
  const int n0  = bform ? 0 : blockIdx.x * 256;
  const int m0  = blockIdx.y * 256;          // M = 768
  const int kc0 = blockIdx.z * CHK;
  const int kc1 = min(VD, kc0 + CHK);
  const int wave = tid >> 6, lane = tid & 63;
  const int wm = wave >> 1, wn = wave & 1;
  const int kq = lane >> 4, ln = lane & 15;
  f32x4 acc[4][8] = {};
  for (int kc = kc0; kc < kc1; kc += 32) {
    __syncthreads();
    { // stage A: 256 rows x 32 k (red_w rows)
      const int m = tid >> 1, kh = (tid & 1) << 4;
      const float* arow = A + (long)(m0 + m) * (long)VD;
      unsigned short tmp[16] __attribute__((aligned(16)));
      if (kc + 32 <= kc1) {
        const float2* ap2 = (const float2*)(arow + kc + kh);
#pragma unroll
        for (int i = 0; i < 8; ++i) { float2 v = ap2[i]; tmp[2*i] = f2bf(v.x); tmp[2*i+1] = f2bf(v.y); }
      } else {
#pragma unroll
        for (int i = 0; i < 16; ++i) {
          int kk = kc + kh + i;
          tmp[i] = f2bf((kk < kc1) ? arow[kk] : 0.f);
        }
      }
      ((int4*)&Al[m][kh])[0] = *(int4*)&tmp[0];
      ((int4*)&Al[m][kh])[1] = *(int4*)&tmp[8];
    }
    if (!bform) {
      const int n = tid >> 1, kh = (tid & 1) << 4;
      const float* bp = vert + (long)(n0 + n) * (long)VD;
      unsigned short tmp[16] __attribute__((aligned(16)));
      if (kc + 32 <= kc1) {
        const float2* bp2 = (const float2*)(bp + kc + kh);
#pragma unroll
        for (int i = 0; i < 8; ++i) { float2 v = bp2[i]; tmp[2*i] = f2bf(v.x); tmp[2*i+1] = f2bf(v.y); }
      } else {
#pragma unroll
        for (int i = 0; i < 16; ++i) {
          int kk = kc + kh + i;
          tmp[i] = f2bf((kk < kc1) ? bp[kk] : 0.f);
        }
      }
      ((int4*)&Bl[n][kh])[0] = *(int4*)&tmp[0];
      ((int4*)&Bl[n][kh])[1] = *(int4*)&tmp[8];
    } else {
      const int n = tid & 255, kh = (tid >> 8) << 4;
      unsigned short tmp[16] __attribute__((aligned(16)));
#pragma unroll
      for (int i = 0; i < 16; ++i) {
        int kk = kc + kh + i;
        float v = 0.f;
        if (kk < kc1 && n < 256) v = fcw[(long)kk * 256 + n];
        tmp[i] = f2bf(v);
      }
      ((int4*)&Bl[n][kh])[0] = *(int4*)&tmp[0];
      ((int4*)&Bl[n][kh])[1] = *(int4*)&tmp[8];
    }
    __syncthreads();
    bf16x8 af[4], bfv[8];
#pragma unroll
    for (int i = 0; i < 4; ++i) af[i] = *(const bf16x8*)&Al[wm*64 + i*16 + ln][kq*8];
#pragma unroll
    for (int j = 0; j < 8; ++j) bfv[j] = *(const bf16x8*)&Bl[wn*128 + j*16 + ln][kq*8];
#pragma unroll
    for (int i = 0; i < 4; ++i)
#pragma unroll
      for (int j = 0; j < 8; ++j)
        acc[i][j] = __builtin_amdgcn_mfma_f32_16x16x32_bf16(af[i], bfv[j], acc[i][j], 0, 0, 0);
  }
#pragma unroll
  for (int i = 0; i < 4; ++i)
#pragma unroll
    for (int j = 0; j < 8; ++j)
#pragma unroll
      for (int r = 0; r < 4; ++r) {
        int gm = m0 + wm*64 + i*16 + kq*4 + r;
        int gn = n0 + wn*128 + j*16 + ln;
        if (gn < N) unsafeAtomicAdd(&C[(long)gm * ldc + gn], acc[i][j][r]);
      }
}

// ---------------- gemv3: EXTRA[v][a] = sum_k {tmpl0,tmpl1,fcb}[k]*redw[a][k]
__global__ __launch_bounds__(256)
void gemv3(const float* __restrict__ redw, const float* __restrict__ tmpl,
           const float* __restrict__ fcb, float* __restrict__ extra)
{
  const int tid = threadIdx.x;
  const int a0 = blockIdx.x * 8;
  const long k0 = (long)blockIdx.y * 8764;
  const long k1 = (k0 + 8764 < (long)VD) ? (k0 + 8764) : (long)VD;
  float s[3][8] = {};
  for (long k = k0 + tid; k < k1; k += 256) {
    const float c0 = tmpl[k], c1 = tmpl[(long)VD + k], cb2 = fcb[k];
#pragma unroll
    for (int r = 0; r < 8; ++r) {
      const float w = redw[(long)(a0 + r) * VD + k];
      s[0][r] += c0 * w; s[1][r] += c1 * w; s[2][r] += cb2 * w;
    }
  }
#pragma unroll
  for (int v = 0; v < 3; ++v)
#pragma unroll
    for (int r = 0; r < 8; ++r) {
      float x = s[v][r];
#pragma unroll
      for (int o = 32; o > 0; o >>= 1) x += __shfl_down(x, o);
      if ((tid & 63) == 0) unsafeAtomicAdd(&extra[v * 768 + a0 + r], x);
    }
}

// ---------------- merged transposes (+red_b fold) + GF odd-row fixup --------
static __device__ __forceinline__ void transpose_body(
    const float* src, int lds, float* dst, int ldd,
    int rows, int cols, const float* bias, int bx, int by)
{
  __shared__ float tile[32][33];
  const int rb = bx * 32, cb = by * 32;
  const int tx = threadIdx.x & 31, ty = threadIdx.x >> 5;
  for (int yy = ty; yy < 32; yy += 8) {
    int c = cb + yy, r = rb + tx;
    tile[yy][tx] = (c < cols && r < rows) ? src[(long)c * lds + r] : 0.f;
  }
  __syncthreads();
  for (int yy = ty; yy < 32; yy += 8) {
    int r = rb + yy, c = cb + tx;
    if (r < rows && c < cols)
      dst[(long)r * ldd + c] = tile[tx][yy] + (bias ? bias[c] : 0.f);
  }
}

__global__ void transpose_merged(const float* __restrict__ OUTG,
                                 const float* __restrict__ OUTM,
                                 const float* __restrict__ extra,
                                 const float* __restrict__ redb,
                                 float* __restrict__ GF, float* __restrict__ MT)
{
  if (blockIdx.z == 0) {
    transpose_body(OUTG, 1024, GF, 768, 1024, 768, redb, blockIdx.x, blockIdx.y);
  } else {
    if (blockIdx.x < 8) {
      transpose_body(OUTM, 256, MT, 768, 256, 768, nullptr, blockIdx.x, blockIdx.y);
    } else if (blockIdx.x == 8 && blockIdx.y == 0) {
      for (int i = threadIdx.x; i < 3 * 768; i += 256) {
        const int b = i / 768, a = i - b * 768;
        GF[(long)(1024 + b) * 768 + a] = extra[i] + redb[a];
      }
    }
  }
}

// ---------------- merged small GEMMs (gihs / PM / M2) -----------------------
__global__ __launch_bounds__(256, 2)
void gemm128x3(const float* __restrict__ hs, const float* __restrict__ wih0,
               float* __restrict__ GIHS, const float* __restrict__ bih0,
               const float* __restrict__ GF, float* __restrict__ PM,
               const float* __restrict__ MT, float* __restrict__ M2)
{
  const float *A, *B, *bias = nullptr; float* C;
  int lda, ldb, M, N, K; long ldc;
  if (blockIdx.z == 0) {
    if (blockIdx.x >= 8) return;
    A = hs; lda = 768; B = wih0; ldb = 1536; C = GIHS; ldc = 768; bias = bih0;
    M = 1024; N = 768; K = 768;
  } else if (blockIdx.z == 1) {
    A = GF; lda = 768; B = wih0 + 768; ldb = 1536; C = PM; ldc = 768;
    M = 1027; N = 768; K = 768;
  } else {
    if (blockIdx.x >= 6 || blockIdx.y >= 2) return;
    A = wih0 + 768; lda = 1536; B = MT; ldb = 768; C = M2; ldc = 256;
    M = 768; N = 256; K = 768;
  }
  __shared__ unsigned short Al[128][40];
  __shared__ unsigned short Bl[128][40];
  const int tid = threadIdx.x;
  const int m0 = blockIdx.x * 128, n0 = blockIdx.y * 128;
  const int wave = tid >> 6, lane = tid & 63;
  const int wm = wave >> 1, wn = wave & 1;
  const int kq = lane >> 4, ln = lane & 15;
  f32x4 acc[4][4] = {};
  for (int kc = 0; kc < K; kc += 32) {
    __syncthreads();
    {
      const int m = tid >> 1, kh = (tid & 1) << 4;
      unsigned short tmp[16] __attribute__((aligned(16)));
      const bool mok = (m0 + m) < M;
      if (mok) {
        const float4* ap4 = (const float4*)(A + (long)(m0 + m) * lda + kc + kh);
#pragma unroll
        for (int i = 0; i < 4; ++i) {
          float4 v = ap4[i];
          tmp[4*i+0] = f2bf(v.x); tmp[4*i+1] = f2bf(v.y);
          tmp[4*i+2] = f2bf(v.z); tmp[4*i+3] = f2bf(v.w);
        }
      } else {
#pragma unroll
        for (int i = 0; i < 16; ++i) tmp[i] = 0;
      }
      ((int4*)&Al[m][kh])[0] = *(int4*)&tmp[0];
      ((int4*)&Al[m][kh])[1] = *(int4*)&tmp[8];
      const int n = m;
      unsigned short tmb[16] __attribute__((aligned(16)));
      const bool nok = (n0 + n) < N;
      if (nok) {
        const float4* bp4 = (const float4*)(B + (long)(n0 + n) * ldb + kc + kh);
#pragma unroll
        for (int i = 0; i < 4; ++i) {
          float4 v = bp4[i];
          tmb[4*i+0] = f2bf(v.x); tmb[4*i+1] = f2bf(v.y);
          tmb[4*i+2] = f2bf(v.z); tmb[4*i+3] = f2bf(v.w);
        }
      } else {
#pragma unroll
        for (int i = 0; i < 16; ++i) tmb[i] = 0;
      }
      ((int4*)&Bl[n][kh])[0] = *(int4*)&tmb[0];
      ((int4*)&Bl[n][kh])[1] = *(int4*)&tmb[8];
    }
    __syncthreads();
    bf16x8 af[4], bfv[4];
#pragma unroll
    for (int i = 0; i < 4; ++i) af[i]  = *(const bf16x8*)&Al[wm*64 + i*16 + ln][kq*8];
#pragma unroll
    for (int j = 0; j < 4; ++j) bfv[j] = *(const bf16x8*)&Bl[wn*64 + j*16 + ln][kq*8];
#pragma unroll
    for (int i = 0; i < 4; ++i)
#pragma unroll
      for (int j = 0; j < 4; ++j)
        acc[i][j] = __builtin_amdgcn_mfma_f32_16x16x32_bf16(af[i], bfv[j], acc[i][j], 0, 0, 0);
  }
#pragma unroll
  for (int i = 0; i < 4; ++i)
#pragma unroll
    for (int j = 0; j < 4; ++j)
#pragma unroll
      for (int r = 0; r < 4; ++r) {
        const int gm = m0 + wm*64 + i*16 + kq*4 + r;
        const int gn = n0 + wn*64 + j*16 + ln;
        if (gm < M && gn < N) {
          float v = acc[i][j][r];
          if (bias) v += bias[gn];
          C[(long)gm * ldc + gn] = v;
        }
      }
}

// ---------------- fused recurrence + fc GEMM --------------------------------
struct ProdLds {
  float wq[24][260], wh0s[24][260], wi1s[24][260], wh1s[24][260];
  float h0c[2][256], h1c[2][256];
  float dotsS[4][2][3][8];     // slots: 0=q 1=gh(l0) 2=gi1 3=gh1
  int tfl[TT];
};
struct ConsLds {
  unsigned short As[128][264];
  unsigned short Bl[128][40];
  float wred[8];
};

#define S_Q  0
#define S_GH 1
#define S_I1 2
#define S_H1 3

#define HALF_DOTS(W, H, MS)                                                   \
  {                                                                           \
    const int g8_ = tid >> 3, l8_ = tid & 7;                                  \
    if (g8_ < 48) {                                                           \
      const int row_ = g8_ >> 1, bb_ = g8_ & 1;                               \
      const float4* w4_ = (const float4*)&(W)[row_][0];                       \
      const float4* h4_ = (const float4*)&(H)[bb_][0];                        \
      float s_ = 0.f;                                                         \
      _Pragma("unroll")                                                       \
      for (int i = 0; i < 8; ++i) {                                           \
        const float4 a_ = w4_[i * 8 + l8_], h_ = h4_[i * 8 + l8_];            \
        s_ += a_.x * h_.x + a_.y * h_.y + a_.z * h_.z + a_.w * h_.w;          \
      }                                                                       \
      s_ += __shfl_xor(s_, 1); s_ += __shfl_xor(s_, 2); s_ += __shfl_xor(s_, 4); \
      if (l8_ == 0) dotsS[MS][bb_][row_ >> 3][row_ & 7] = s_;                 \
    }                                                                         \
  }

#define POLL_ISSUE(buf, var)                                                  \
  unsigned long long var = __hip_atomic_load(&(buf)[tid], __ATOMIC_RELAXED, __HIP_MEMORY_SCOPE_AGENT);
#define POLL_FINISH(buf, var, dstLds, want)                                   \
  {                                                                           \
    const unsigned w_ = (unsigned)(want); int sp_ = 0;                        \
    while ((unsigned)(var >> 32) < w_ && ++sp_ < (1 << 15)) {                 \
      __builtin_amdgcn_s_sleep(1);                                            \
      var = __hip_atomic_load(&(buf)[tid], __ATOMIC_RELAXED, __HIP_MEMORY_SCOPE_AGENT); \
    }                                                                         \
    ((float*)dstLds)[tid] = __uint_as_float((unsigned)var);                   \
  }
#define POLLP(buf, dstLds, want)                                              \
  { POLL_ISSUE(buf, pw_); POLL_FINISH(buf, pw_, dstLds, want); }

__global__ __launch_bounds__(512, 1)
void k3_fused(const float* __restrict__ gihs, const float* __restrict__ Pm,
              const float* __restrict__ M2m,
              const float* __restrict__ whh0, const float* __restrict__ bhh0,
              const float* __restrict__ wih1, const float* __restrict__ bih1,
              const float* __restrict__ whh1, const float* __restrict__ bhh1,
              const int* __restrict__ tfm,
              unsigned short* __restrict__ h1sb,
              unsigned long long* __restrict__ h0p, unsigned long long* __restrict__ h1p,
              unsigned* __restrict__ prog,
              const float* __restrict__ fcw, const float* __restrict__ fcb,
              const float* __restrict__ vert,
              float* __restrict__ out, float* __restrict__ lossp)
{
  __shared__ union { ProdLds p; ConsLds c; } U;
  const int tid = threadIdx.x;

  if (blockIdx.x >= 32) {
    // ================= CONSUMER: fc GEMM tile sweep ========================
    auto& C = U.c;
    const int idx = blockIdx.x - 32;
    int tx, memb, cnt;
    if (idx < 24)      { tx = 0; memb = (idx)      >> 1; cnt = 12; }
    else if (idx < 48) { tx = 1; memb = (idx - 24) >> 1; cnt = 12; }
    else if (idx < 96) { tx = 2; memb = (idx - 48) >> 1; cnt = 24; }
    else               { tx = 3; memb = (idx - 96) >> 1; cnt = 64; }
    const int b = idx & 1;
    const int nt0 = memb * 548 / cnt, nt1 = (memb + 1) * 548 / cnt;
    if (nt0 >= nt1) return;
    const unsigned want = (unsigned)((tx + 1) * 128);
    if (tid < 32) {
      int sp = 0;
      while (__hip_atomic_load(&prog[tid * 16], __ATOMIC_RELAXED, __HIP_MEMORY_SCOPE_AGENT) < want) {
        if (++sp > (1 << 14)) break;
        for (int j = 0; j < 16; ++j) __builtin_amdgcn_s_sleep(15);
      }
    }
    __syncthreads();
    const long rbase = (long)b * 512 + (long)tx * 128;
    {
      const unsigned long long* src = (const unsigned long long*)(h1sb + rbase * 256);
#pragma unroll
      for (int i = 0; i < 16; ++i) {
        const int u = tid * 16 + i;
        unsigned long long v = __hip_atomic_load(&src[u], __ATOMIC_RELAXED, __HIP_MEMORY_SCOPE_AGENT);
        const int row = u >> 6, c4 = u & 63;
        *(unsigned long long*)&C.As[row][c4 * 4] = v;
      }
    }
    __syncthreads();
    const int wave = tid >> 6, lane = tid & 63;
    const int wm = wave >> 2, wn = wave & 3;
    const int kq = lane >> 4, ln = lane & 15;
    for (int nt = nt0; nt < nt1; ++nt) {
      const int n0 = nt * 128;
      f32x4 acc[4][2] = {};
#pragma unroll 1
      for (int ks = 0; ks < 8; ++ks) {
        __syncthreads();
        {
          const int rn = tid >> 2, kh = (tid & 3) * 8;
          const int gn = n0 + rn;
          unsigned short tmb[8] __attribute__((aligned(16)));
          if (gn < VD) {
            const float4* bp = (const float4*)&fcw[(long)gn * 256 + ks * 32 + kh];
            float4 v0 = bp[0], v1 = bp[1];
            tmb[0] = f2bf(v0.x); tmb[1] = f2bf(v0.y); tmb[2] = f2bf(v0.z); tmb[3] = f2bf(v0.w);
            tmb[4] = f2bf(v1.x); tmb[5] = f2bf(v1.y); tmb[6] = f2bf(v1.z); tmb[7] = f2bf(v1.w);
          } else {
#pragma unroll
            for (int i = 0; i < 8; ++i) tmb[i] = 0;
          }
          *(int4*)&C.Bl[rn][kh] = *(int4*)tmb;
        }
        __syncthreads();
        bf16x8 af[4], bfv[2];
#pragma unroll
        for (int i = 0; i < 4; ++i)
          af[i] = *(const bf16x8*)&C.As[wm*64 + i*16 + ln][ks*32 + kq*8];
#pragma unroll
        for (int j = 0; j < 2; ++j)
          bfv[j] = *(const bf16x8*)&C.Bl[wn*32 + j*16 + ln][kq*8];
#pragma unroll
        for (int i = 0; i < 4; ++i)
#pragma unroll
          for (int j = 0; j < 2; ++j)
            acc[i][j] = __builtin_amdgcn_mfma_f32_16x16x32_bf16(af[i], bfv[j], acc[i][j], 0, 0, 0);
      }
      float ls = 0.f;
#pragma unroll
      for (int i = 0; i < 4; ++i)
#pragma unroll
        for (int j = 0; j < 2; ++j)
#pragma unroll
          for (int r = 0; r < 4; ++r) {
            const int gmL = wm*64 + i*16 + kq*4 + r;
            const int gn = n0 + wn*32 + j*16 + ln;
            if (gn < VD) {
              const float v = acc[i][j][r] + fcb[gn];
              const long grow = rbase + gmL;
              out[grow * VD + gn] = v;
              const float dd = v - vert[grow * VD + gn];
              ls += dd * dd;
            }
          }
#pragma unroll
      for (int o = 32; o > 0; o >>= 1) ls += __shfl_down(ls, o);
      if (lane == 0) C.wred[wave] = ls;
      __syncthreads();
      if (tid == 0) {
        float s = 0.f;
#pragma unroll
        for (int w = 0; w < 8; ++w) s += C.wred[w];
        lossp[(tx * 2 + b) * 548 + nt] = s;
      }
      __syncthreads();
    }
    return;
  }

  // ================= PRODUCER: A-ahead pipelined GRU recurrence ============
  float (&wq)[24][260]   = U.p.wq;
  float (&wh0s)[24][260] = U.p.wh0s;
  float (&wi1s)[24][260] = U.p.wi1s;
  float (&wh1s)[24][260] = U.p.wh1s;
  float (&h0c)[2][256]   = U.p.h0c;
  float (&h1c)[2][256]   = U.p.h1c;
  float (&dotsS)[4][2][3][8] = U.p.dotsS;
  int   (&tfl)[TT]       = U.p.tfl;
  const int wg = blockIdx.x;
  const int j0 = wg * 8;

  {
    const int col = tid & 255, rh = tid >> 8;
    for (int row = rh; row < 24; row += 2) {
      const int g = row >> 3, jj = row & 7;
      const long gr = g * 256 + j0 + jj;
      wq[row][col]   = M2m[gr * 256 + col];
      wh0s[row][col] = whh0[gr * 256 + col];
      wi1s[row][col] = wih1[gr * 256 + col];
      wh1s[row][col] = whh1[gr * 256 + col];
    }
  }
  ((float*)h0c)[tid] = 0.f;
  ((float*)h1c)[tid] = 0.f;
  if (tid < TT) tfl[tid] = tfm[tid];

  // combine thread mapping (valid for tid<32): cb = batch, cj = owned h dim
  const int cb = (tid >> 3) & 1, cjj = tid & 7, cj = j0 + cjj;
  float bh0v[3], bi1v[3], bh1v[3], d2v[3];
  if (tid < 16) {                 // combineA regs
#pragma unroll
    for (int g = 0; g < 3; ++g) {
      bh0v[g] = bhh0[g*256 + cj];
      d2v[g]  = Pm[(long)1026 * 768 + g*256 + cj];
    }
  } else if (tid < 32) {          // combineB regs
#pragma unroll
    for (int g = 0; g < 3; ++g) {
      bi1v[g] = bih1[g*256 + cj];
      bh1v[g] = bhh1[g*256 + cj];
    }
  }
  __syncthreads();

  const int wave = tid >> 6;
  // prefetch regs for combineA of the CURRENT iteration t: gihs_{t+1}, P_t
  float gihsv[3], piv[3];
  // ---- prologue: A(0) (h0 = 0, teacher-forced c0term path) ----------------
  if (tid < 16) {
#pragma unroll
    for (int g = 0; g < 3; ++g) {
      gihsv[g] = gihs[((long)cb * TT) * 768 + g*256 + cj];      // gihs_0
      piv[g]   = Pm[(long)(1024 + cb) * 768 + g*256 + cj];      // c0term
    }
  }
  HALF_DOTS(wh0s, h0c, S_GH);
  __syncthreads();
  if (tid < 16) {
    float gi[3], gh[3];
#pragma unroll
    for (int g = 0; g < 3; ++g) {
      gi[g] = gihsv[g] + piv[g];
      gh[g] = dotsS[S_GH][cb][g][cjj] + bh0v[g];
    }
    const float rr = 1.f / (1.f + __expf(-(gi[0] + gh[0])));
    const float zz = 1.f / (1.f + __expf(-(gi[1] + gh[1])));
    const float nn = tanhf(gi[2] + rr * gh[2]);
    const float h0n = (1.f - zz) * nn;    // + z*0
    const unsigned long long pk =
        ((unsigned long long)1u << 32) | (unsigned long long)__float_as_uint(h0n);
    __hip_atomic_store(&h0p[512 + cb * 256 + cj], pk,       // tag 1, slot 1
                       __ATOMIC_RELAXED, __HIP_MEMORY_SCOPE_AGENT);
    // prefetch for iteration 0: gihs_1, P_0
#pragma unroll
    for (int g = 0; g < 3; ++g) {
      gihsv[g] = gihs[((long)cb * TT + 1) * 768 + g*256 + cj];
      piv[g]   = Pm[((long)cb * TT + 0) * 768 + g*256 + cj];
    }
  }
  __syncthreads();
  POLLP(h0p + 512, h0c, 1);     // h0c = h0_0
  __syncthreads();

  for (int t = 0; t < TT - 1; ++t) {
    const int tfc = tfl[t];     // does A(t+1) take the teacher-forced path?
    if (tfc) {
      // ---- one shared exchange window: A(t+1) + B(t) together -------------
      HALF_DOTS(wh0s, h0c, S_GH);
      HALF_DOTS(wi1s, h0c, S_I1);
      HALF_DOTS(wh1s, h1c, S_H1);
      __syncthreads();
      if (tid < 16) {           // combineA -> h0_{t+1}
        float gi[3], gh[3];
#pragma unroll
        for (int g = 0; g < 3; ++g) {
          gi[g] = gihsv[g] + piv[g];
          gh[g] = dotsS[S_GH][cb][g][cjj] + bh0v[g];
        }
        const float rr = 1.f / (1.f + __expf(-(gi[0] + gh[0])));
        const float zz = 1.f / (1.f + __expf(-(gi[1] + gh[1])));
        const float nn = tanhf(gi[2] + rr * gh[2]);
        const float h0n = (1.f - zz) * nn + zz * h0c[cb][cj];
        const unsigned long long pk =
            ((unsigned long long)(unsigned)(t + 2) << 32) | (unsigned long long)__float_as_uint(h0n);
        __hip_atomic_store(&h0p[(t & 1) * 512 + cb * 256 + cj], pk,
                           __ATOMIC_RELAXED, __HIP_MEMORY_SCOPE_AGENT);
        if (t + 1 < TT - 1) {   // prefetch for iteration t+1
#pragma unroll
          for (int g = 0; g < 3; ++g) {
            gihsv[g] = gihs[((long)cb * TT + (t + 2)) * 768 + g*256 + cj];
            piv[g]   = Pm[((long)cb * TT + (t + 1)) * 768 + g*256 + cj];
          }
        }
      } else if (tid < 32) {    // combineB -> h1_t
        float gi[3], gh[3];
#pragma unroll
        for (int g = 0; g < 3; ++g) {
          gi[g] = dotsS[S_I1][cb][g][cjj] + bi1v[g];
          gh[g] = dotsS[S_H1][cb][g][cjj] + bh1v[g];
        }
        const float rr = 1.f / (1.f + __expf(-(gi[0] + gh[0])));
        const float zz = 1.f / (1.f + __expf(-(gi[1] + gh[1])));
        const float nn = tanhf(gi[2] + rr * gh[2]);
        const float h1n = (1.f - zz) * nn + zz * h1c[cb][cj];
        const unsigned hb = (unsigned)f2bf(h1n);
        asm volatile("global_store_short %0, %1, off sc0 sc1"
                     :: "v"(&h1sb[((long)cb * TT + t) * 256 + cj]), "v"(hb) : "memory");
        const unsigned long long pk =
            ((unsigned long long)(unsigned)(t + 1) << 32) | (unsigned long long)__float_as_uint(h1n);
        __hip_atomic_store(&h1p[((t + 1) & 1) * 512 + cb * 256 + cj], pk,
                           __ATOMIC_RELAXED, __HIP_MEMORY_SCOPE_AGENT);
      }
      __syncthreads();
      // dual-poll: both loads in flight -> one shared round trip
      POLL_ISSUE(h0p + (t & 1) * 512, pa);
      POLL_ISSUE(h1p + ((t + 1) & 1) * 512, pb);
      POLL_FINISH(h0p + (t & 1) * 512, pa, h0c, t + 2);
      POLL_FINISH(h1p + ((t + 1) & 1) * 512, pb, h1c, t + 1);
      __syncthreads();
    } else {
      // ---- tf=0: B(t) -> h1 exchange -> A(t+1) (q-path) -> h0 exchange ----
      HALF_DOTS(wi1s, h0c, S_I1);
      HALF_DOTS(wh1s, h1c, S_H1);
      __syncthreads();
      if (tid >= 16 && tid < 32) {  // combineB -> h1_t
        float gi[3], gh[3];
#pragma unroll
        for (int g = 0; g < 3; ++g) {
          gi[g] = dotsS[S_I1][cb][g][cjj] + bi1v[g];
          gh[g] = dotsS[S_H1][cb][g][cjj] + bh1v[g];
        }
        const float rr = 1.f / (1.f + __expf(-(gi[0] + gh[0])));
        const float zz = 1.f / (1.f + __expf(-(gi[1] + gh[1])));
        const float nn = tanhf(gi[2] + rr * gh[2]);
        const float h1n = (1.f - zz) * nn + zz * h1c[cb][cj];
        const unsigned hb = (unsigned)f2bf(h1n);
        asm volatile("global_store_short %0, %1, off sc0 sc1"
                     :: "v"(&h1sb[((long)cb * TT + t) * 256 + cj]), "v"(hb) : "memory");
        const unsigned long long pk =
            ((unsigned long long)(unsigned)(t + 1) << 32) | (unsigned long long)__float_as_uint(h1n);
        __hip_atomic_store(&h1p[((t + 1) & 1) * 512 + cb * 256 + cj], pk,
                           __ATOMIC_RELAXED, __HIP_MEMORY_SCOPE_AGENT);
      }
      __syncthreads();              // h1c readers done before fill
      POLL_ISSUE(h1p + ((t + 1) & 1) * 512, pq);
      HALF_DOTS(wh0s, h0c, S_GH);   // overlap h1 round trip
      POLL_FINISH(h1p + ((t + 1) & 1) * 512, pq, h1c, t + 1);
      __syncthreads();
      HALF_DOTS(wq, h1c, S_Q);
      __syncthreads();
      if (tid < 16) {               // combineA (q-path) -> h0_{t+1}
        float gi[3], gh[3];
#pragma unroll
        for (int g = 0; g < 3; ++g) {
          const float q = dotsS[S_Q][cb][g][cjj] + d2v[g];
          gi[g] = gihsv[g] + q;
          gh[g] = dotsS[S_GH][cb][g][cjj] + bh0v[g];
        }
        const float rr = 1.f / (1.f + __expf(-(gi[0] + gh[0])));
        const float zz = 1.f / (1.f + __expf(-(gi[1] + gh[1])));
        const float nn = tanhf(gi[2] + rr * gh[2]);
        const float h0n = (1.f - zz) * nn + zz * h0c[cb][cj];
        const unsigned long long pk =
            ((unsigned long long)(unsigned)(t + 2) << 32) | (unsigned long long)__float_as_uint(h0n);
        __hip_atomic_store(&h0p[(t & 1) * 512 + cb * 256 + cj], pk,
                           __ATOMIC_RELAXED, __HIP_MEMORY_SCOPE_AGENT);
        if (t + 1 < TT - 1) {
#pragma unroll
          for (int g = 0; g < 3; ++g) {
            gihsv[g] = gihs[((long)cb * TT + (t + 2)) * 768 + g*256 + cj];
            piv[g]   = Pm[((long)cb * TT + (t + 1)) * 768 + g*256 + cj];
          }
        }
      }
      __syncthreads();
      POLLP(h0p + (t & 1) * 512, h0c, t + 2);
      __syncthreads();
    }
    if ((t & 15) == 15) {  // lazy progress publish (h1 rows <= t done)
      if (wave == 0) asm volatile("s_waitcnt vmcnt(0)" ::: "memory");
      if (tid == 0)
        __hip_atomic_store(&prog[wg * 16], (unsigned)(t + 1),
                           __ATOMIC_RELAXED, __HIP_MEMORY_SCOPE_AGENT);
    }
    __syncthreads();
  }
  // ---- epilogue: B(TT-1) ---------------------------------------------------
  {
    const int t = TT - 1;
    HALF_DOTS(wi1s, h0c, S_I1);
    HALF_DOTS(wh1s, h1c, S_H1);
    __syncthreads();
    if (tid >= 16 && tid < 32) {
      float gi[3], gh[3];
#pragma unroll
      for (int g = 0; g < 3; ++g) {
        gi[g] = dotsS[S_I1][cb][g][cjj] + bi1v[g];
        gh[g] = dotsS[S_H1][cb][g][cjj] + bh1v[g];
      }
      const float rr = 1.f / (1.f + __expf(-(gi[0] + gh[0])));
      const float zz = 1.f / (1.f + __expf(-(gi[1] + gh[1])));
      const float nn = tanhf(gi[2] + rr * gh[2]);
      const float h1n = (1.f - zz) * nn + zz * h1c[cb][cj];
      const unsigned hb = (unsigned)f2bf(h1n);
      asm volatile("global_store_short %0, %1, off sc0 sc1"
                   :: "v"(&h1sb[((long)cb * TT + t) * 256 + cj]), "v"(hb) : "memory");
    }
    if (wave == 0) asm volatile("s_waitcnt vmcnt(0)" ::: "memory");
    if (tid == 0)
      __hip_atomic_store(&prog[wg * 16], (unsigned)TT,
                         __ATOMIC_RELAXED, __HIP_MEMORY_SCOPE_AGENT);
  }
}

__global__ void loss_finalize(const float* __restrict__ lossp, int n, float* __restrict__ out) {
  __shared__ float red[256];
  float s = 0.f;
  for (int i = threadIdx.x; i < n; i += 256) s += lossp[i];
  red[threadIdx.x] = s;
  __syncthreads();
  for (int st = 128; st > 0; st >>= 1) {
    if (threadIdx.x < st) red[threadIdx.x] += red[threadIdx.x + st];
    __syncthreads();
  }
  if (threadIdx.x == 0) out[0] = red[0] * (1.0f / 71792640.0f);
}

// ---------------------------------------------------------------------------
extern "C" void kernel_launch(void* const* d_in, const int* in_sizes, int n_in,
                              void* d_out, int out_size, void* d_ws, size_t ws_size,
                              hipStream_t stream) {
  (void)in_sizes; (void)n_in; (void)out_size; (void)ws_size;
  const float* hs   = (const float*)d_in[0];
  const float* tmpl = (const float*)d_in[1];
  const float* vert = (const float*)d_in[2];
  const int*   tfm  = (const int*)  d_in[3];
  const float* wih0 = (const float*)d_in[4];
  const float* whh0 = (const float*)d_in[5];
  const float* bih0 = (const float*)d_in[6];
  const float* bhh0 = (const float*)d_in[7];
  const float* wih1 = (const float*)d_in[8];
  const float* whh1 = (const float*)d_in[9];
  const float* bih1 = (const float*)d_in[10];
  const float* bhh1 = (const float*)d_in[11];
  const float* fcw  = (const float*)d_in[12];
  const float* fcb  = (const float*)d_in[13];
  const float* redw = (const float*)d_in[14];
  const float* redb = (const float*)d_in[15];
  float* out = (float*)d_out;

  char* ws = (char*)d_ws;
  float*    LOSSP = (float*)(ws + 0);          // overlaps OUTG (dead after transpose)
  float*    OUTG  = (float*)(ws + 0);          // [768][1024]
  float*    OUTM  = (float*)(ws + 3145728);    // [768][256]
  float*    EXTRA = (float*)(ws + 3932160);    // [3][768]
  unsigned long long* H0P = (unsigned long long*)(ws + 3941376); // [2][512]
  unsigned long long* H1P = (unsigned long long*)(ws + 3949568); // [2][512]
  unsigned* PROG  = (unsigned*)(ws + 3957760); // 32 slots x 16 stride
  float*    GF    = (float*)(ws + 3960064);    // [1027][768]
  float*    MT    = (float*)(ws + 7115776);    // [256][768]
  float*    GIHS  = (float*)(ws + 7902208);    // [1024][768]
  float*    PM    = (float*)(ws + 11047936);   // [1027][768]
  float*    M2    = (float*)(ws + 14203648);   // [768][256]
  unsigned short* H1SB = (unsigned short*)(ws + 14990080); // [1024][256] bf16

  // zero split-K accumulators + EXTRA + tag buffers + progress (every call)
  hipMemsetAsync(d_ws, 0, 3960064, stream);

  // merged big V-contractions
  bigk_merged<<<dim3(5, 3, 21), 512, 0, stream>>>(redw, vert, fcw, OUTG, OUTM, 3344);
  gemv3<<<dim3(96, 8), 256, 0, stream>>>(redw, tmpl, fcb, EXTRA);

  // merged transposes (+red_b fold) + GF odd-row fixup
  transpose_merged<<<dim3(32, 24, 2), 256, 0, stream>>>(OUTG, OUTM, EXTRA, redb, GF, MT);

  // merged small GEMMs: gihs / PM / M2
  gemm128x3<<<dim3(9, 6, 3), 256, 0, stream>>>(hs, wih0, GIHS, bih0, GF, PM, MT, M2);

  // fused recurrence (32 producer WGs) + fc GEMM/MSE (224 consumer WGs)
  k3_fused<<<256, 512, 0, stream>>>(GIHS, PM, M2, whh0, bhh0, wih1, bih1, whh1, bhh1,
                                    tfm, H1SB, H0P, H1P, PROG,
                                    fcw, fcb, vert, out, LOSSP);

  loss_finalize<<<1, 256, 0, stream>>>(LOSSP, 4384, out + 71792640L);
}